// Round 7
// baseline (341.971 us; speedup 1.0000x reference)
//
#include <hip/hip_runtime.h>

// AttentionLayer: B=16, T=S=C=E=1024, NORM_C=0.5
// out  = (ctx @ w_out^T + b_out + x) * sqrt(.5)   [f32]
// attn = softmax(mask(h @ K))                     [f32]
// R6: reg-staged GEMM pipeline (T14). No global_load_lds -> compiler-precise
//     vmcnt via register deps; raw s_barrier keeps prefetch in flight.
//     128x128 BK=64, 4 waves, 2x32KB LDS dbuf, XOR bank swizzle both sides.

#define SCALE_F 0.70710678118654752440f

constexpr int BB = 16, TT = 1024, SS = 1024, CC = 1024, EE = 1024;

typedef float    f32x4 __attribute__((ext_vector_type(4)));
typedef _Float16 f16x8 __attribute__((ext_vector_type(8)));
typedef _Float16 f16x4 __attribute__((ext_vector_type(4)));

#define LGKM0()  asm volatile("s_waitcnt lgkmcnt(0)" ::: "memory")
#define SBAR()   asm volatile("s_barrier" ::: "memory")

// ---------------------------------------------------------------- conversions
__global__ __launch_bounds__(256) void cvt_f16(const float* __restrict__ s,
                                               _Float16* __restrict__ d, long n) {
  long i = ((long)blockIdx.x * 256 + threadIdx.x) * 8;
  if (i >= n) return;
  f32x4 a = *(const f32x4*)(s + i);
  f32x4 b = *(const f32x4*)(s + i + 4);
  f16x8 h;
  h[0]=(_Float16)a[0]; h[1]=(_Float16)a[1]; h[2]=(_Float16)a[2]; h[3]=(_Float16)a[3];
  h[4]=(_Float16)b[0]; h[5]=(_Float16)b[1]; h[6]=(_Float16)b[2]; h[7]=(_Float16)b[3];
  *(f16x8*)(d + i) = h;
}

// src: [B][R][Cc] f32  ->  dst: [B][Cc][R] f16
__global__ __launch_bounds__(256) void transpose_cvt(const float* __restrict__ src,
                                                     _Float16* __restrict__ dst,
                                                     int R, int Cc) {
  __shared__ float tile[64][65];
  const int b = blockIdx.z;
  const int r0 = blockIdx.y * 64, c0 = blockIdx.x * 64;
  const int t = threadIdx.x;
  const int tr = t >> 4, tc4 = (t & 15) * 4;
  const float* s = src + (size_t)b * R * Cc;
#pragma unroll
  for (int i = 0; i < 4; ++i) {
    f32x4 v = *(const f32x4*)(s + (size_t)(r0 + i * 16 + tr) * Cc + c0 + tc4);
    tile[i * 16 + tr][tc4 + 0] = v[0]; tile[i * 16 + tr][tc4 + 1] = v[1];
    tile[i * 16 + tr][tc4 + 2] = v[2]; tile[i * 16 + tr][tc4 + 3] = v[3];
  }
  __syncthreads();
  _Float16* d = dst + (size_t)b * Cc * R;
#pragma unroll
  for (int j = 0; j < 4; ++j) {
    const int cl = j * 16 + tr;
    f16x4 h;
    h[0] = (_Float16)tile[tc4 + 0][cl]; h[1] = (_Float16)tile[tc4 + 1][cl];
    h[2] = (_Float16)tile[tc4 + 2][cl]; h[3] = (_Float16)tile[tc4 + 3][cl];
    *(f16x4*)(d + (size_t)(c0 + cl) * R + r0 + tc4) = h;
  }
}

// ------------------------------------------------------------------- mask prep
__global__ __launch_bounds__(256) void mask_prep(const unsigned char* __restrict__ mraw,
                                                 float* __restrict__ maskneg,
                                                 float* __restrict__ sscale) {
  const int b = blockIdx.x, t = threadIdx.x;
  __shared__ int bytemode_sh, cnt_sh;
  if (t == 0) { bytemode_sh = 0; cnt_sh = 0; }
  __syncthreads();
  const unsigned int* mu = (const unsigned int*)mraw;
  int local = 0;
  for (int i = t; i < (BB * SS) / 4; i += 256) {
    unsigned int v = mu[i];
    if (v != 0u && v != 1u && v != 0x3f800000u) local = 1;
  }
  if (local) atomicOr(&bytemode_sh, 1);
  __syncthreads();
  const int bytemode = bytemode_sh;
  int cnt = 0;
  for (int s = t; s < SS; s += 256) {
    int m = bytemode ? (mraw[b * SS + s] != 0) : (mu[b * SS + s] != 0u);
    maskneg[b * SS + s] = m ? -__builtin_inff() : 0.0f;
    cnt += m;
  }
#pragma unroll
  for (int o = 32; o; o >>= 1) cnt += __shfl_down(cnt, o);
  if ((t & 63) == 0) atomicAdd(&cnt_sh, cnt);
  __syncthreads();
  if (t == 0) {
    float sv = (float)SS - (float)cnt_sh;
    sscale[b] = sv * rsqrtf(sv);
  }
}

// ---------------------------------------------------------------------- GEMM
// C[M,N] = A[M,K] @ Bmat[N,K]^T ; fp16 K-major, f32 accum.
// BM=BN=128, BK=64; 256 thr = 4 waves (2x2); wave tile 64x64 (acc[4][4]).
// Reg-staged pipeline: iter u reads buf[u&1]; ds_writes tile u+1 (from regs,
// loaded last iter -> compiler's precise vmcnt covers ~1 tile of latency);
// issues tile u+2's 8 global_load_dwordx4; 32 MFMA; lgkm0+s_barrier (NO
// vmcnt drain -> prefetch stays in flight across the barrier).
// Swizzle: row r (128B, 8x16B slots): logical chunk c stored at slot c^(r&7).
template <int EPI>
__global__ __launch_bounds__(256, 2)
void gemm_rs(const _Float16* __restrict__ A, const _Float16* __restrict__ Bmat,
             long aStride, long bStride, long oStride,
             int M, int N, int K,
             void* __restrict__ outp,
             const float* __restrict__ bias,
             const float* __restrict__ addmat,
             const float* __restrict__ extra) {
  constexpr int BM = 128, BN = 128, BK = 64;
  __shared__ __attribute__((aligned(16))) _Float16 smem[2][(BM + BN) * BK];  // 64 KB

  const int t = threadIdx.x;
  const int lane = t & 63;
  const int wid = t >> 6;
  const int wr = wid >> 1, wc = wid & 1;
  const int z = blockIdx.z;
  const int lo = lane & 15, hi = lane >> 4;
  const int sx = lo & 7;
  const int nt = K >> 6;

  // XCD-aware bijective swizzle (gx*gy % 8 == 0 for all our grids)
  const int gx = gridDim.x;
  const int fblk = blockIdx.x + blockIdx.y * gx;
  const int q = (gx * gridDim.y) >> 3;
  const int wg = (fblk & 7) * q + (fblk >> 3);
  const long rowBase = (long)(wg / gx) * BM;
  const long colBase = (long)(wg % gx) * BN;

  const _Float16* Ag = A + (size_t)z * aStride + rowBase * K;
  const _Float16* Bg = Bmat + (size_t)z * bStride + colBase * K;

  // staging map: thread t covers row t>>1 (0..127), slots (t&1)*4 .. +3
  const int srow = t >> 1;
  const int sh4 = (t & 1) * 4;

  f16x8 ra[4], rb[4];     // staged tile (A,B) in registers
  f32x4 acc[4][4] = {};

  auto gload = [&](int u) {
    const _Float16* ap = Ag + (size_t)srow * K + u * 64 + sh4 * 8;
    const _Float16* bp = Bg + (size_t)srow * K + u * 64 + sh4 * 8;
#pragma unroll
    for (int i = 0; i < 4; ++i) ra[i] = *(const f16x8*)(ap + i * 8);
#pragma unroll
    for (int i = 0; i < 4; ++i) rb[i] = *(const f16x8*)(bp + i * 8);
  };
  auto swrite = [&](int buf) {
    _Float16* As = &smem[buf][0];
    _Float16* Bs = &smem[buf][BM * BK];
    const int rb8 = srow & 7;
#pragma unroll
    for (int i = 0; i < 4; ++i)
      *(f16x8*)&As[srow * 64 + ((sh4 + i) ^ rb8) * 8] = ra[i];
#pragma unroll
    for (int i = 0; i < 4; ++i)
      *(f16x8*)&Bs[srow * 64 + ((sh4 + i) ^ rb8) * 8] = rb[i];
  };

  // prologue: tile0 -> LDS buf0; tile1 staged in regs
  gload(0);
  swrite(0);
  gload(1);
  LGKM0();
  SBAR();

  for (int u = 0; u < nt; ++u) {
    const _Float16* As = &smem[u & 1][0];
    const _Float16* Bs = &smem[u & 1][BM * BK];
    f16x8 a[2][4], b[2][4];
#pragma unroll
    for (int ks = 0; ks < 2; ++ks) {
      const int slot = (ks * 4 + hi) ^ sx;
#pragma unroll
      for (int mi = 0; mi < 4; ++mi)
        a[ks][mi] = *(const f16x8*)&As[(wr * 64 + mi * 16 + lo) * 64 + slot * 8];
#pragma unroll
      for (int ni = 0; ni < 4; ++ni)
        b[ks][ni] = *(const f16x8*)&Bs[(wc * 64 + ni * 16 + lo) * 64 + slot * 8];
    }
    if (u + 1 < nt) swrite((u + 1) & 1);   // vmcnt(reg-dep): waits last iter's loads
    if (u + 2 < nt) gload(u + 2);          // issue next-next tile early
    __builtin_amdgcn_s_setprio(1);
#pragma unroll
    for (int ks = 0; ks < 2; ++ks)
#pragma unroll
      for (int mi = 0; mi < 4; ++mi)
#pragma unroll
        for (int ni = 0; ni < 4; ++ni)
          acc[mi][ni] = __builtin_amdgcn_mfma_f32_16x16x32_f16(
              a[ks][mi], b[ks][ni], acc[mi][ni], 0, 0, 0);
    __builtin_amdgcn_s_setprio(0);
    LGKM0();                               // own ds_reads+ds_writes drained
    SBAR();                                // writes visible; vmcnt NOT drained
  }

  // ---- vectorized epilogue: wave-private LDS transpose to row-major chunks
  constexpr int EPS = 68;
  const int fr = lane & 15;
  const int fq = (lane >> 4) * 4;
  const int er = lane >> 2;
  const int ec = (lane & 3) * 16;
  const long gc0 = colBase + wc * 64 + ec;
  float* ep = (float*)&smem[0][0] + wid * (16 * EPS);

  f32x4 biasv[4], maskv[4], av[4];
  float sc = 0.f;
  if constexpr (EPI == 1 || EPI == 4) {
#pragma unroll
    for (int i = 0; i < 4; ++i) biasv[i] = *(const f32x4*)&bias[gc0 + i * 4];
    const long gr0 = rowBase + wr * 64 + er;
#pragma unroll
    for (int i = 0; i < 4; ++i) av[i] = *(const f32x4*)&addmat[gr0 * N + gc0 + i * 4];
  }
  if constexpr (EPI == 2) {
#pragma unroll
    for (int i = 0; i < 4; ++i) maskv[i] = *(const f32x4*)&extra[(size_t)z * N + gc0 + i * 4];
  }
  if constexpr (EPI == 3) sc = extra[z];

#pragma unroll
  for (int m = 0; m < 4; ++m) {
#pragma unroll
    for (int n = 0; n < 4; ++n)
#pragma unroll
      for (int j = 0; j < 4; ++j)
        ep[(fq + j) * EPS + n * 16 + fr] = acc[m][n][j];
    __syncthreads();
    const long gr = rowBase + wr * 64 + m * 16 + er;
    f32x4 r[4];
#pragma unroll
    for (int i = 0; i < 4; ++i) r[i] = *(const f32x4*)&ep[er * EPS + ec + i * 4];
    f32x4 a_cur[4];
    if constexpr (EPI == 1 || EPI == 4) {
#pragma unroll
      for (int i = 0; i < 4; ++i) a_cur[i] = av[i];
      if (m < 3) {
        const long grn = gr + 16;
#pragma unroll
        for (int i = 0; i < 4; ++i) av[i] = *(const f32x4*)&addmat[grn * N + gc0 + i * 4];
      }
    }
    if constexpr (EPI == 1) {
      _Float16* o = (_Float16*)outp + gr * N + gc0;
#pragma unroll
      for (int g = 0; g < 2; ++g) {
        f32x4 v0 = (r[2 * g] + biasv[2 * g] + a_cur[2 * g]) * SCALE_F;
        f32x4 v1 = (r[2 * g + 1] + biasv[2 * g + 1] + a_cur[2 * g + 1]) * SCALE_F;
        f16x8 h;
        h[0]=(_Float16)v0[0]; h[1]=(_Float16)v0[1]; h[2]=(_Float16)v0[2]; h[3]=(_Float16)v0[3];
        h[4]=(_Float16)v1[0]; h[5]=(_Float16)v1[1]; h[6]=(_Float16)v1[2]; h[7]=(_Float16)v1[3];
        *(f16x8*)(o + g * 8) = h;
      }
    } else if constexpr (EPI == 2) {
      float* o = (float*)outp + (size_t)z * oStride + gr * N + gc0;
#pragma unroll
      for (int i = 0; i < 4; ++i) *(f32x4*)(o + i * 4) = r[i] + maskv[i];
    } else if constexpr (EPI == 3) {
      _Float16* o = (_Float16*)outp + (size_t)z * oStride + gr * N + gc0;
#pragma unroll
      for (int g = 0; g < 2; ++g) {
        f32x4 v0 = r[2 * g] * sc;
        f32x4 v1 = r[2 * g + 1] * sc;
        f16x8 h;
        h[0]=(_Float16)v0[0]; h[1]=(_Float16)v0[1]; h[2]=(_Float16)v0[2]; h[3]=(_Float16)v0[3];
        h[4]=(_Float16)v1[0]; h[5]=(_Float16)v1[1]; h[6]=(_Float16)v1[2]; h[7]=(_Float16)v1[3];
        *(f16x8*)(o + g * 8) = h;
      }
    } else {
      float* o = (float*)outp + gr * N + gc0;
#pragma unroll
      for (int i = 0; i < 4; ++i)
        *(f32x4*)(o + i * 4) = (r[i] + biasv[i] + a_cur[i]) * SCALE_F;
    }
    __syncthreads();
  }
}

// -------------------------------------------------------------------- softmax
__global__ __launch_bounds__(256) void softmax_k(float* __restrict__ attn,
                                                 _Float16* __restrict__ attn16) {
  const size_t row = blockIdx.x;
  float* p = attn + row * SS;
  const int t = threadIdx.x;
  f32x4 v = *(const f32x4*)(p + t * 4);
  __shared__ float red[8];
  float m = fmaxf(fmaxf(v[0], v[1]), fmaxf(v[2], v[3]));
#pragma unroll
  for (int o = 32; o; o >>= 1) m = fmaxf(m, __shfl_xor(m, o));
  if (!(t & 63)) red[t >> 6] = m;
  __syncthreads();
  m = fmaxf(fmaxf(red[0], red[1]), fmaxf(red[2], red[3]));
  f32x4 e;
  e[0] = __expf(v[0] - m); e[1] = __expf(v[1] - m);
  e[2] = __expf(v[2] - m); e[3] = __expf(v[3] - m);
  float s = e[0] + e[1] + e[2] + e[3];
#pragma unroll
  for (int o = 32; o; o >>= 1) s += __shfl_xor(s, o);
  if (!(t & 63)) red[4 + (t >> 6)] = s;
  __syncthreads();
  s = red[4] + red[5] + red[6] + red[7];
  const float inv = 1.0f / s;
  f32x4 o4; o4[0]=e[0]*inv; o4[1]=e[1]*inv; o4[2]=e[2]*inv; o4[3]=e[3]*inv;
  *(f32x4*)(p + t * 4) = o4;
  f16x4 h; h[0]=(_Float16)o4[0]; h[1]=(_Float16)o4[1];
  h[2]=(_Float16)o4[2]; h[3]=(_Float16)o4[3];
  *(f16x4*)(attn16 + row * SS + t * 4) = h;
}

// -------------------------------------------------------------------- launch
extern "C" void kernel_launch(void* const* d_in, const int* in_sizes, int n_in,
                              void* d_out, int out_size, void* d_ws, size_t ws_size,
                              hipStream_t stream) {
  const float* x     = (const float*)d_in[0];
  const float* te    = (const float*)d_in[1];
  const float* keys  = (const float*)d_in[2];
  const float* vals  = (const float*)d_in[3];
  const void*  mask  = d_in[4];
  const float* w_in  = (const float*)d_in[5];
  const float* b_in  = (const float*)d_in[6];
  const float* w_out = (const float*)d_in[7];
  const float* b_out = (const float*)d_in[8];

  char* ws = (char*)d_ws;
  const size_t MB32 = 33554432;
  _Float16* buf0   = (_Float16*)(ws);
  _Float16* buf1   = (_Float16*)(ws + MB32);
  _Float16* keysT  = (_Float16*)(ws + 2 * MB32);
  _Float16* valsT  = (_Float16*)(ws + 3 * MB32);
  _Float16* win16  = (_Float16*)(ws + 4 * MB32);
  _Float16* wout16 = (_Float16*)(ws + 4 * MB32 + 2097152);
  float*    maskneg= (float*)   (ws + 4 * MB32 + 2 * 2097152);
  float*    sscale = (float*)   (ws + 4 * MB32 + 2 * 2097152 + 65536);

  float* out_main = (float*)d_out;
  float* attn_out = (float*)d_out + (size_t)BB * TT * CC;

  cvt_f16<<<dim3(16777216 / 2048), 256, 0, stream>>>(x, buf0, 16777216);
  cvt_f16<<<dim3(1048576 / 2048), 256, 0, stream>>>(w_in, win16, 1048576);
  cvt_f16<<<dim3(1048576 / 2048), 256, 0, stream>>>(w_out, wout16, 1048576);
  transpose_cvt<<<dim3(SS / 64, EE / 64, BB), 256, 0, stream>>>(keys, keysT, EE, SS);
  transpose_cvt<<<dim3(EE / 64, SS / 64, BB), 256, 0, stream>>>(vals, valsT, SS, EE);
  mask_prep<<<dim3(BB), 256, 0, stream>>>((const unsigned char*)mask, maskneg, sscale);

  gemm_rs<1><<<dim3(EE / 128, (BB * TT) / 128, 1), 256, 0, stream>>>(
      buf0, win16, 0, 0, 0, BB * TT, EE, CC, buf1, b_in, te, nullptr);
  gemm_rs<2><<<dim3(SS / 128, TT / 128, BB), 256, 0, stream>>>(
      buf1, keysT, (long)TT * EE, (long)SS * EE, (long)TT * SS,
      TT, SS, EE, attn_out, nullptr, nullptr, maskneg);
  softmax_k<<<dim3(BB * TT), 256, 0, stream>>>(attn_out, buf1);
  gemm_rs<3><<<dim3(EE / 128, TT / 128, BB), 256, 0, stream>>>(
      buf1, valsT, (long)TT * SS, (long)EE * SS, (long)TT * EE,
      TT, EE, SS, buf0, nullptr, nullptr, sscale);
  gemm_rs<4><<<dim3(CC / 128, (BB * TT) / 128, 1), 256, 0, stream>>>(
      buf0, wout16, 0, 0, 0, BB * TT, CC, EE, out_main, b_out, x, nullptr);
}

// Round 9
// 314.833 us; speedup vs baseline: 1.0862x; 1.0862x over previous
//
#include <hip/hip_runtime.h>

// AttentionLayer: B=16, T=S=C=E=1024, NORM_C=0.5
// out  = (ctx @ w_out^T + b_out + x) * sqrt(.5)   [f32]
// attn = softmax(mask(h @ K))                     [f32]
// R9: R8 + the missing vmcnt->barrier pairing (per-wave vmcnt doesn't cover
//     other waves' staged loads; SBAR after VMCNT makes the ledger global).

#define SCALE_F 0.70710678118654752440f

constexpr int BB = 16, TT = 1024, SS = 1024, CC = 1024, EE = 1024;

typedef float    f32x4 __attribute__((ext_vector_type(4)));
typedef _Float16 f16x8 __attribute__((ext_vector_type(8)));
typedef _Float16 f16x4 __attribute__((ext_vector_type(4)));

__device__ __forceinline__ void gload_lds16(const _Float16* g, _Float16* l) {
  __builtin_amdgcn_global_load_lds((const __attribute__((address_space(1))) void*)g,
                                   (__attribute__((address_space(3))) void*)l,
                                   16, 0, 0);
}

#define VMCNT(N) asm volatile("s_waitcnt vmcnt(" #N ")" ::: "memory")
#define LGKM(N)  asm volatile("s_waitcnt lgkmcnt(" #N ")" ::: "memory")
#define SBAR()   asm volatile("s_barrier" ::: "memory")
// asm ds_read: no "memory" clobber -> compiler inserts no waits; we count.
#define DSR(dst, a, off) \
  asm volatile("ds_read_b128 %0, %1 offset:" #off : "=v"(dst) : "v"(a))

// ---------------------------------------------------------------- conversions
__global__ __launch_bounds__(256) void cvt_f16(const float* __restrict__ s,
                                               _Float16* __restrict__ d, long n) {
  long i = ((long)blockIdx.x * 256 + threadIdx.x) * 8;
  if (i >= n) return;
  f32x4 a = *(const f32x4*)(s + i);
  f32x4 b = *(const f32x4*)(s + i + 4);
  f16x8 h;
  h[0]=(_Float16)a[0]; h[1]=(_Float16)a[1]; h[2]=(_Float16)a[2]; h[3]=(_Float16)a[3];
  h[4]=(_Float16)b[0]; h[5]=(_Float16)b[1]; h[6]=(_Float16)b[2]; h[7]=(_Float16)b[3];
  *(f16x8*)(d + i) = h;
}

// src: [B][R][Cc] f32  ->  dst: [B][Cc][R] f16
__global__ __launch_bounds__(256) void transpose_cvt(const float* __restrict__ src,
                                                     _Float16* __restrict__ dst,
                                                     int R, int Cc) {
  __shared__ float tile[64][65];
  const int b = blockIdx.z;
  const int r0 = blockIdx.y * 64, c0 = blockIdx.x * 64;
  const int t = threadIdx.x;
  const int tr = t >> 4, tc4 = (t & 15) * 4;
  const float* s = src + (size_t)b * R * Cc;
#pragma unroll
  for (int i = 0; i < 4; ++i) {
    f32x4 v = *(const f32x4*)(s + (size_t)(r0 + i * 16 + tr) * Cc + c0 + tc4);
    tile[i * 16 + tr][tc4 + 0] = v[0]; tile[i * 16 + tr][tc4 + 1] = v[1];
    tile[i * 16 + tr][tc4 + 2] = v[2]; tile[i * 16 + tr][tc4 + 3] = v[3];
  }
  __syncthreads();
  _Float16* d = dst + (size_t)b * Cc * R;
#pragma unroll
  for (int j = 0; j < 4; ++j) {
    const int cl = j * 16 + tr;
    f16x4 h;
    h[0] = (_Float16)tile[tc4 + 0][cl]; h[1] = (_Float16)tile[tc4 + 1][cl];
    h[2] = (_Float16)tile[tc4 + 2][cl]; h[3] = (_Float16)tile[tc4 + 3][cl];
    *(f16x4*)(d + (size_t)(c0 + cl) * R + r0 + tc4) = h;
  }
}

// ------------------------------------------------------------------- mask prep
__global__ __launch_bounds__(256) void mask_prep(const unsigned char* __restrict__ mraw,
                                                 float* __restrict__ maskneg,
                                                 float* __restrict__ sscale) {
  const int b = blockIdx.x, t = threadIdx.x;
  __shared__ int bytemode_sh, cnt_sh;
  if (t == 0) { bytemode_sh = 0; cnt_sh = 0; }
  __syncthreads();
  const unsigned int* mu = (const unsigned int*)mraw;
  int local = 0;
  for (int i = t; i < (BB * SS) / 4; i += 256) {
    unsigned int v = mu[i];
    if (v != 0u && v != 1u && v != 0x3f800000u) local = 1;
  }
  if (local) atomicOr(&bytemode_sh, 1);
  __syncthreads();
  const int bytemode = bytemode_sh;
  int cnt = 0;
  for (int s = t; s < SS; s += 256) {
    int m = bytemode ? (mraw[b * SS + s] != 0) : (mu[b * SS + s] != 0u);
    maskneg[b * SS + s] = m ? -__builtin_inff() : 0.0f;
    cnt += m;
  }
#pragma unroll
  for (int o = 32; o; o >>= 1) cnt += __shfl_down(cnt, o);
  if ((t & 63) == 0) atomicAdd(&cnt_sh, cnt);
  __syncthreads();
  if (t == 0) {
    float sv = (float)SS - (float)cnt_sh;
    sscale[b] = sv * rsqrtf(sv);
  }
}

// ---------------------------------------------------------------------- GEMM
// C[M,N] = A[M,K] @ Bmat[N,K]^T ; fp16 K-major, f32 accum.
// BM=BN=256, BK=64; 512 thr = 8 waves (wm 0..1, wn 0..3); wave tile 128x64.
// LDS 128KB: buf(2) x {A [256][64], B [256][64]}, rows 128B (8x16B slots);
// slot s of row r holds k-chunk s^(r&7) (both sides involution).
// Per tile u:
//   DSR x24 (asm, invisible to compiler waitcnt)
//   LGKM(12) -> MFMA ks0 (setprio)
//   LGKM(0)  -> SBAR            (all waves done reading buf[u&1])
//   STAGE8(u+2 -> buf[u&1])     (overwrite-safe)
//   MFMA ks1 (setprio)
//   VMCNT(8) -> SBAR            (ALL waves' tile-u+1 loads landed: per-wave
//                                vmcnt + rendezvous = global guarantee)
template <int EPI>
__global__ __launch_bounds__(512, 2)
void gemm256(const _Float16* __restrict__ A, const _Float16* __restrict__ Bmat,
             long aStride, long bStride, long oStride,
             int M, int N, int K,
             void* __restrict__ outp,
             const float* __restrict__ bias,
             const float* __restrict__ addmat,
             const float* __restrict__ extra) {
  __shared__ __attribute__((aligned(16))) _Float16 smem[65536];  // 128 KB

  const int t = threadIdx.x;
  const int lane = t & 63;
  const int wid = t >> 6;
  const int wm = wid >> 2, wn = wid & 3;
  const int z = blockIdx.z;
  const int lo = lane & 15, hi = lane >> 4;
  const int sx = lo & 7;
  const int nt = K >> 6;                     // 16

  // XCD-aware bijective swizzle (gx*gy % 8 == 0 for all our grids)
  const int gx = gridDim.x;
  const int fblk = blockIdx.x + blockIdx.y * gx;
  const int q = (gx * gridDim.y) >> 3;
  const int wg = (fblk & 7) * q + (fblk >> 3);
  const long rowBase = (long)(wg / gx) * 256;
  const long colBase = (long)(wg % gx) * 256;

  const _Float16* Ag = A + (size_t)z * aStride + rowBase * K;
  const _Float16* Bg = Bmat + (size_t)z * bStride + colBase * K;

  // staging: call i covers LDS rows i*64 + (t>>3), slot t&7 (dest linear in
  // lane); source k-chunk inverse-swizzled.
  const int sr8 = t >> 3;                              // 0..63
  const int srck = (((t & 7) ^ (sr8 & 7)) << 3);       // elems

  f32x4 acc[8][4] = {};

#define STAGE8(U)                                                              \
  {                                                                            \
    const int tu_ = (U);                                                       \
    _Float16* db_ = &smem[(tu_ & 1) * 32768];                                  \
    const size_t kb_ = (size_t)tu_ * 64 + srck;                                \
    _Pragma("unroll") for (int i_ = 0; i_ < 4; ++i_)                           \
      gload_lds16(Ag + (size_t)(i_ * 64 + sr8) * K + kb_,                      \
                  db_ + i_ * 4096 + t * 8);                                    \
    _Pragma("unroll") for (int i_ = 0; i_ < 4; ++i_)                           \
      gload_lds16(Bg + (size_t)(i_ * 64 + sr8) * K + kb_,                      \
                  db_ + 16384 + i_ * 4096 + t * 8);                            \
  }

  // lane-invariant LDS byte bases (buf 0)
  const int lds0 = (int)(size_t)&smem[0];
  const int abase = lds0 + (wm * 128 + lo) * 128 + ((hi ^ sx) << 4);
  const int bbase = lds0 + 32768 + (wn * 64 + lo) * 128 + ((hi ^ sx) << 4);

  STAGE8(0)
  STAGE8(1)
  VMCNT(8);          // own tile-0 loads landed
  SBAR();            // ... and everyone else's

  for (int u = 0; u < nt; ++u) {
    const int bo = (u & 1) << 16;
    const int aad = abase + bo, bad = bbase + bo;
    const int aad1 = aad ^ 64, bad1 = bad ^ 64;
    f16x8 a0[8], b0[4], a1[8], b1[4];
    DSR(a0[0], aad, 0);     DSR(a0[1], aad, 2048);  DSR(a0[2], aad, 4096);
    DSR(a0[3], aad, 6144);  DSR(a0[4], aad, 8192);  DSR(a0[5], aad, 10240);
    DSR(a0[6], aad, 12288); DSR(a0[7], aad, 14336);
    DSR(b0[0], bad, 0);     DSR(b0[1], bad, 2048);  DSR(b0[2], bad, 4096);
    DSR(b0[3], bad, 6144);
    DSR(a1[0], aad1, 0);     DSR(a1[1], aad1, 2048);  DSR(a1[2], aad1, 4096);
    DSR(a1[3], aad1, 6144);  DSR(a1[4], aad1, 8192);  DSR(a1[5], aad1, 10240);
    DSR(a1[6], aad1, 12288); DSR(a1[7], aad1, 14336);
    DSR(b1[0], bad1, 0);     DSR(b1[1], bad1, 2048);  DSR(b1[2], bad1, 4096);
    DSR(b1[3], bad1, 6144);
    LGKM(12);                                  // ks0 frags ready
    __builtin_amdgcn_sched_barrier(0);
    __builtin_amdgcn_s_setprio(1);
#pragma unroll
    for (int mi = 0; mi < 8; ++mi)
#pragma unroll
      for (int ni = 0; ni < 4; ++ni)
        acc[mi][ni] = __builtin_amdgcn_mfma_f32_16x16x32_f16(a0[mi], b0[ni],
                                                             acc[mi][ni], 0, 0, 0);
    __builtin_amdgcn_s_setprio(0);
    LGKM(0);                                   // all own reads of this buf done
    __builtin_amdgcn_sched_barrier(0);
    SBAR();                                    // all waves done reading buf
    if (u + 2 < nt) STAGE8(u + 2)              // overwrite-safe now
    __builtin_amdgcn_s_setprio(1);
#pragma unroll
    for (int mi = 0; mi < 8; ++mi)
#pragma unroll
      for (int ni = 0; ni < 4; ++ni)
        acc[mi][ni] = __builtin_amdgcn_mfma_f32_16x16x32_f16(a1[mi], b1[ni],
                                                             acc[mi][ni], 0, 0, 0);
    __builtin_amdgcn_s_setprio(0);
    if (u + 2 < nt)       { VMCNT(8); }        // own u+1 landed; u+2 in flight
    else if (u + 2 == nt) { VMCNT(0); }        // drain final tile
    SBAR();                                    // rendezvous: u+1 landed globally
  }

  // ---- vectorized epilogue: per-wave LDS transpose to row-major 16-col chunks
  constexpr int EPS = 68;
  const int fr = lane & 15;
  const int fq = (lane >> 4) * 4;
  const int er = lane >> 2;
  const int ec = (lane & 3) * 16;
  const long gc0 = colBase + wn * 64 + ec;
  float* ep = (float*)smem + wid * (16 * EPS);

  f32x4 biasv[4], maskv[4], av[4];
  float sc = 0.f;
  if constexpr (EPI == 1 || EPI == 4) {
#pragma unroll
    for (int i = 0; i < 4; ++i) biasv[i] = *(const f32x4*)&bias[gc0 + i * 4];
    const long gr0 = rowBase + wm * 128 + er;
#pragma unroll
    for (int i = 0; i < 4; ++i) av[i] = *(const f32x4*)&addmat[gr0 * N + gc0 + i * 4];
  }
  if constexpr (EPI == 2) {
#pragma unroll
    for (int i = 0; i < 4; ++i) maskv[i] = *(const f32x4*)&extra[(size_t)z * N + gc0 + i * 4];
  }
  if constexpr (EPI == 3) sc = extra[z];

  __syncthreads();
#pragma unroll
  for (int mf = 0; mf < 8; ++mf) {
#pragma unroll
    for (int n = 0; n < 4; ++n)
#pragma unroll
      for (int j = 0; j < 4; ++j)
        ep[(fq + j) * EPS + n * 16 + fr] = acc[mf][n][j];
    __syncthreads();
    const long gr = rowBase + wm * 128 + mf * 16 + er;
    f32x4 r[4];
#pragma unroll
    for (int i = 0; i < 4; ++i) r[i] = *(const f32x4*)&ep[er * EPS + ec + i * 4];
    f32x4 a_cur[4];
    if constexpr (EPI == 1 || EPI == 4) {
#pragma unroll
      for (int i = 0; i < 4; ++i) a_cur[i] = av[i];
      if (mf < 7) {
        const long grn = gr + 16;
#pragma unroll
        for (int i = 0; i < 4; ++i) av[i] = *(const f32x4*)&addmat[grn * N + gc0 + i * 4];
      }
    }
    if constexpr (EPI == 1) {
      _Float16* o = (_Float16*)outp + gr * N + gc0;
#pragma unroll
      for (int g = 0; g < 2; ++g) {
        f32x4 v0 = (r[2 * g] + biasv[2 * g] + a_cur[2 * g]) * SCALE_F;
        f32x4 v1 = (r[2 * g + 1] + biasv[2 * g + 1] + a_cur[2 * g + 1]) * SCALE_F;
        f16x8 h;
        h[0]=(_Float16)v0[0]; h[1]=(_Float16)v0[1]; h[2]=(_Float16)v0[2]; h[3]=(_Float16)v0[3];
        h[4]=(_Float16)v1[0]; h[5]=(_Float16)v1[1]; h[6]=(_Float16)v1[2]; h[7]=(_Float16)v1[3];
        *(f16x8*)(o + g * 8) = h;
      }
    } else if constexpr (EPI == 2) {
      float* o = (float*)outp + (size_t)z * oStride + gr * N + gc0;
#pragma unroll
      for (int i = 0; i < 4; ++i) *(f32x4*)(o + i * 4) = r[i] + maskv[i];
    } else if constexpr (EPI == 3) {
      _Float16* o = (_Float16*)outp + (size_t)z * oStride + gr * N + gc0;
#pragma unroll
      for (int g = 0; g < 2; ++g) {
        f32x4 v0 = r[2 * g] * sc;
        f32x4 v1 = r[2 * g + 1] * sc;
        f16x8 h;
        h[0]=(_Float16)v0[0]; h[1]=(_Float16)v0[1]; h[2]=(_Float16)v0[2]; h[3]=(_Float16)v0[3];
        h[4]=(_Float16)v1[0]; h[5]=(_Float16)v1[1]; h[6]=(_Float16)v1[2]; h[7]=(_Float16)v1[3];
        *(f16x8*)(o + g * 8) = h;
      }
    } else {
      float* o = (float*)outp + gr * N + gc0;
#pragma unroll
      for (int i = 0; i < 4; ++i)
        *(f32x4*)(o + i * 4) = (r[i] + biasv[i] + a_cur[i]) * SCALE_F;
    }
    __syncthreads();
  }
}

// -------------------------------------------------------------------- softmax
__global__ __launch_bounds__(256) void softmax_k(float* __restrict__ attn,
                                                 _Float16* __restrict__ attn16) {
  const size_t row = blockIdx.x;
  float* p = attn + row * SS;
  const int t = threadIdx.x;
  f32x4 v = *(const f32x4*)(p + t * 4);
  __shared__ float red[8];
  float m = fmaxf(fmaxf(v[0], v[1]), fmaxf(v[2], v[3]));
#pragma unroll
  for (int o = 32; o; o >>= 1) m = fmaxf(m, __shfl_xor(m, o));
  if (!(t & 63)) red[t >> 6] = m;
  __syncthreads();
  m = fmaxf(fmaxf(red[0], red[1]), fmaxf(red[2], red[3]));
  f32x4 e;
  e[0] = __expf(v[0] - m); e[1] = __expf(v[1] - m);
  e[2] = __expf(v[2] - m); e[3] = __expf(v[3] - m);
  float s = e[0] + e[1] + e[2] + e[3];
#pragma unroll
  for (int o = 32; o; o >>= 1) s += __shfl_xor(s, o);
  if (!(t & 63)) red[4 + (t >> 6)] = s;
  __syncthreads();
  s = red[4] + red[5] + red[6] + red[7];
  const float inv = 1.0f / s;
  f32x4 o4; o4[0]=e[0]*inv; o4[1]=e[1]*inv; o4[2]=e[2]*inv; o4[3]=e[3]*inv;
  *(f32x4*)(p + t * 4) = o4;
  f16x4 h; h[0]=(_Float16)o4[0]; h[1]=(_Float16)o4[1];
  h[2]=(_Float16)o4[2]; h[3]=(_Float16)o4[3];
  *(f16x4*)(attn16 + row * SS + t * 4) = h;
}

// -------------------------------------------------------------------- launch
extern "C" void kernel_launch(void* const* d_in, const int* in_sizes, int n_in,
                              void* d_out, int out_size, void* d_ws, size_t ws_size,
                              hipStream_t stream) {
  const float* x     = (const float*)d_in[0];
  const float* te    = (const float*)d_in[1];
  const float* keys  = (const float*)d_in[2];
  const float* vals  = (const float*)d_in[3];
  const void*  mask  = d_in[4];
  const float* w_in  = (const float*)d_in[5];
  const float* b_in  = (const float*)d_in[6];
  const float* w_out = (const float*)d_in[7];
  const float* b_out = (const float*)d_in[8];

  char* ws = (char*)d_ws;
  const size_t MB32 = 33554432;
  _Float16* buf0   = (_Float16*)(ws);
  _Float16* buf1   = (_Float16*)(ws + MB32);
  _Float16* keysT  = (_Float16*)(ws + 2 * MB32);
  _Float16* valsT  = (_Float16*)(ws + 3 * MB32);
  _Float16* win16  = (_Float16*)(ws + 4 * MB32);
  _Float16* wout16 = (_Float16*)(ws + 4 * MB32 + 2097152);
  float*    maskneg= (float*)   (ws + 4 * MB32 + 2 * 2097152);
  float*    sscale = (float*)   (ws + 4 * MB32 + 2 * 2097152 + 65536);

  float* out_main = (float*)d_out;
  float* attn_out = (float*)d_out + (size_t)BB * TT * CC;

  cvt_f16<<<dim3(16777216 / 2048), 256, 0, stream>>>(x, buf0, 16777216);
  cvt_f16<<<dim3(1048576 / 2048), 256, 0, stream>>>(w_in, win16, 1048576);
  cvt_f16<<<dim3(1048576 / 2048), 256, 0, stream>>>(w_out, wout16, 1048576);
  transpose_cvt<<<dim3(SS / 64, EE / 64, BB), 256, 0, stream>>>(keys, keysT, EE, SS);
  transpose_cvt<<<dim3(EE / 64, SS / 64, BB), 256, 0, stream>>>(vals, valsT, SS, EE);
  mask_prep<<<dim3(BB), 256, 0, stream>>>((const unsigned char*)mask, maskneg, sscale);

  gemm256<1><<<dim3(EE / 256, (BB * TT) / 256, 1), 512, 0, stream>>>(
      buf0, win16, 0, 0, 0, BB * TT, EE, CC, buf1, b_in, te, nullptr);
  gemm256<2><<<dim3(SS / 256, TT / 256, BB), 512, 0, stream>>>(
      buf1, keysT, (long)TT * EE, (long)SS * EE, (long)TT * SS,
      TT, SS, EE, attn_out, nullptr, nullptr, maskneg);
  softmax_k<<<dim3(BB * TT), 256, 0, stream>>>(attn_out, buf1);
  gemm256<3><<<dim3(EE / 256, TT / 256, BB), 512, 0, stream>>>(
      buf1, valsT, (long)TT * SS, (long)EE * SS, (long)TT * EE,
      TT, EE, SS, buf0, nullptr, nullptr, sscale);
  gemm256<4><<<dim3(CC / 256, (BB * TT) / 256, 1), 512, 0, stream>>>(
      buf0, wout16, 0, 0, 0, BB * TT, CC, EE, out_main, b_out, x, nullptr);
}